// Round 4
// baseline (258.543 us; speedup 1.0000x reference)
//
#include <hip/hip_runtime.h>

#define N_NODES 50000
#define E_EDGES 800000
#define D_DIM   128
#define LN_EPS  1e-5f
#define SCAN_BLOCKS 196   // ceil(50000/256)
#define GEMM_BLOCKS 391   // ceil(50000/128)
#define HIST4_BLOCKS 782  // ceil(800000/1024), 4 edges/thread
#define SCAT_BLOCKS  391  // ceil(800000/2048), 8 edges/thread
#define GSLICE_BLOCKS 50000 // 6250 node-octets x 8 (slice x parity)
#define FINAL_BLOCKS 12500  // 4 nodes/block

typedef __bf16 bf16x8 __attribute__((ext_vector_type(8)));
typedef unsigned short ushort8v __attribute__((ext_vector_type(8)));
typedef float f32x4 __attribute__((ext_vector_type(4)));
typedef int i32x2v __attribute__((ext_vector_type(2)));
typedef int i32x16v __attribute__((ext_vector_type(16)));

// fp32 -> bf16 (round to nearest even), stored as raw ushort
__device__ inline unsigned short f2b(float f) {
    unsigned int u = __float_as_uint(f);
    unsigned int r = u + 0x7FFFu + ((u >> 16) & 1u);
    return (unsigned short)(r >> 16);
}
__device__ inline float b2f(unsigned short h) {
    return __uint_as_float((unsigned int)h << 16);
}

// Scalar (SMEM) loads of wave-uniform sev batches: 8 edges / s_load_dwordx16.
// waitcnt fused in the asm so consumers can't be hoisted past it (rule #18).
__device__ inline i32x16v sload16(const uint2* p) {
    i32x16v r;
    asm volatile("s_load_dwordx16 %0, %1, 0x0\n\ts_waitcnt lgkmcnt(0)"
                 : "=&s"(r) : "s"(p));
    return r;
}
__device__ inline i32x2v sload2(const uint2* p) {
    i32x2v r;
    asm volatile("s_load_dwordx2 %0, %1, 0x0\n\ts_waitcnt lgkmcnt(0)"
                 : "=&s"(r) : "s"(p));
    return r;
}

// ---------------- K_prep: zero count/done; pack W into bf16 hi/lo B-frags --
__global__ void k_prep(const float* __restrict__ W,
                       unsigned short* __restrict__ Whp,
                       unsigned short* __restrict__ Wlp,
                       int* __restrict__ count, int* __restrict__ done) {
    int i = blockIdx.x * 256 + threadIdx.x;
    if (i == 0) *done = 0;
    if (i < N_NODES) count[i] = 0;
    if (i < 16384) {
        int o = i >> 7, k = i & 127;
        float v = W[i];                       // W[o][k], coalesced
        unsigned short h = f2b(v);
        unsigned short l = f2b(v - b2f(h));
        int idx = (k >> 3) * 1024 + o * 8 + (k & 7);
        Whp[idx] = h;
        Wlp[idx] = l;
    }
}

// ---------------- K1: fused [MFMA gemm blocks] + [hist/rank blocks] --------
// GEMM: h = x @ W^T via mfma_f32_16x16x32_bf16, 3-term bf16 split.
// Epilogue transposes acc through LDS (W buffer is dead) so hb stores are
// 8x16B coalesced per thread. Hist: 4 edges/thread, rank saved to erank.
__global__ __launch_bounds__(256, 2) void k_gemm_hist(
        const float* __restrict__ xin, const unsigned short* __restrict__ Wpk,
        const float* __restrict__ Wa, const int* __restrict__ dst,
        int* __restrict__ count, int* __restrict__ erank,
        unsigned short* __restrict__ hb,
        float* __restrict__ ssrc, float* __restrict__ sdst) {
    __shared__ float4 wl4[4096];   // 64 KB: [0,2048) = W hi, [2048,4096) = W lo
    const int tid = threadIdx.x;

    if (blockIdx.x >= GEMM_BLOCKS) {
        int e0 = (blockIdx.x - GEMM_BLOCKS) * 1024 + tid * 4;
        if (e0 < E_EDGES) {                   // e0 % 4 == 0 -> full quad valid
            int4 dv = *(const int4*)&dst[e0];
            int r0 = atomicAdd(&count[dv.x], 1);
            int r1 = atomicAdd(&count[dv.y], 1);
            int r2 = atomicAdd(&count[dv.z], 1);
            int r3 = atomicAdd(&count[dv.w], 1);
            *(int4*)&erank[e0] = make_int4(r0, r1, r2, r3);
        }
        return;
    }

    // stage packed W (hi plane then lo plane, contiguous 64 KB)
    {
        const float4* wsrc = (const float4*)Wpk;
        #pragma unroll
        for (int i = 0; i < 16; ++i)
            wl4[i * 256 + tid] = wsrc[i * 256 + tid];
    }

    const int c = tid & 15;          // A row / B col / D col within tile
    const int g = (tid >> 4) & 3;    // k-group within wave
    const int w = tid >> 6;          // wave id: rows w*32 .. w*32+31
    const int n0 = blockIdx.x * 128;

    // A fragments: rows n0 + w*32 + t*16 + c, k = s*32 + g*8 + j (j=0..7)
    bf16x8 ah[2][4], al[2][4];
    #pragma unroll
    for (int t = 0; t < 2; ++t) {
        int n = n0 + w * 32 + t * 16 + c;
        if (n > N_NODES - 1) n = N_NODES - 1;          // clamp tail rows
        const float* xr = xin + (size_t)n * 128;
        #pragma unroll
        for (int s = 0; s < 4; ++s) {
            float4 f0 = *(const float4*)(xr + s * 32 + g * 8);
            float4 f1 = *(const float4*)(xr + s * 32 + g * 8 + 4);
            float fv[8] = {f0.x, f0.y, f0.z, f0.w, f1.x, f1.y, f1.z, f1.w};
            ushort8v uh, ul;
            #pragma unroll
            for (int j = 0; j < 8; ++j) {
                unsigned short hj = f2b(fv[j]);
                uh[j] = hj;
                ul[j] = f2b(fv[j] - b2f(hj));
            }
            ah[t][s] = __builtin_bit_cast(bf16x8, uh);
            al[t][s] = __builtin_bit_cast(bf16x8, ul);
        }
    }

    __syncthreads();                 // LDS W staging complete
    const bf16x8* wb = (const bf16x8*)wl4;

    f32x4 acc[2][8];
    #pragma unroll
    for (int t = 0; t < 2; ++t)
        #pragma unroll
        for (int cb = 0; cb < 8; ++cb)
            acc[t][cb] = (f32x4){0.f, 0.f, 0.f, 0.f};

    #pragma unroll
    for (int cb = 0; cb < 8; ++cb) {
        #pragma unroll
        for (int s = 0; s < 4; ++s) {
            int q = (s * 4 + g) * 128 + cb * 16 + c;
            bf16x8 bh = wb[q];           // one ds_read_b128 each
            bf16x8 bl = wb[2048 + q];
            acc[0][cb] = __builtin_amdgcn_mfma_f32_16x16x32_bf16(ah[0][s], bh, acc[0][cb], 0, 0, 0);
            acc[1][cb] = __builtin_amdgcn_mfma_f32_16x16x32_bf16(ah[1][s], bh, acc[1][cb], 0, 0, 0);
            acc[0][cb] = __builtin_amdgcn_mfma_f32_16x16x32_bf16(al[0][s], bh, acc[0][cb], 0, 0, 0);
            acc[1][cb] = __builtin_amdgcn_mfma_f32_16x16x32_bf16(al[1][s], bh, acc[1][cb], 0, 0, 0);
            acc[0][cb] = __builtin_amdgcn_mfma_f32_16x16x32_bf16(ah[0][s], bl, acc[0][cb], 0, 0, 0);
            acc[1][cb] = __builtin_amdgcn_mfma_f32_16x16x32_bf16(ah[1][s], bl, acc[1][cb], 0, 0, 0);
        }
    }

    // ssrc/sdst: reduce across the 16 c-lanes (register-only, before LDS reuse)
    float asv[8], adv[8];
    #pragma unroll
    for (int cb = 0; cb < 8; ++cb) {
        asv[cb] = Wa[cb * 16 + c];
        adv[cb] = Wa[128 + cb * 16 + c];
    }
    #pragma unroll
    for (int t = 0; t < 2; ++t) {
        #pragma unroll
        for (int i = 0; i < 4; ++i) {
            int n = n0 + w * 32 + t * 16 + g * 4 + i;
            float ps = 0.f, pd = 0.f;
            #pragma unroll
            for (int cb = 0; cb < 8; ++cb) {
                float v = acc[t][cb][i];
                ps += v * asv[cb];
                pd += v * adv[cb];
            }
            #pragma unroll
            for (int off = 1; off < 16; off <<= 1) {
                ps += __shfl_xor(ps, off);
                pd += __shfl_xor(pd, off);
            }
            if (c == 0 && n < N_NODES) { ssrc[n] = ps; sdst[n] = pd; }
        }
    }

    // hb epilogue: transpose through LDS (W buffer dead), coalesced stores
    __syncthreads();                 // all waves done reading W from wl4
    unsigned short* hlds = (unsigned short*)wl4;   // [128][128] ushort = 32 KB
    #pragma unroll
    for (int t = 0; t < 2; ++t)
        #pragma unroll
        for (int cb = 0; cb < 8; ++cb)
            #pragma unroll
            for (int i = 0; i < 4; ++i)
                hlds[(w * 32 + t * 16 + g * 4 + i) * 128 + cb * 16 + c] =
                    f2b(acc[t][cb][i]);
    __syncthreads();
    #pragma unroll
    for (int ii = 0; ii < 8; ++ii) {
        int cidx = ii * 256 + tid;    // 2048 chunks of 16 B
        int row = cidx >> 4, off = cidx & 15;
        int n = n0 + row;
        if (n < N_NODES) {
            ushort8v v = *(const ushort8v*)&hlds[row * 128 + off * 8];
            *(ushort8v*)&hb[(size_t)n * 128 + off * 8] = v;
        }
    }
}

// ---------------- K2: fused two-level exclusive scan (last-block finishes) -
__global__ __launch_bounds__(256) void k_scan(const int* __restrict__ count,
                                              int* __restrict__ rowptr,
                                              int* __restrict__ bsum,
                                              int* __restrict__ done) {
    __shared__ int wsum[4];
    __shared__ int amLast;
    const int tid  = threadIdx.x;
    const int lane = tid & 63, w = tid >> 6;
    int i = blockIdx.x * 256 + tid;
    int v = (i < N_NODES) ? count[i] : 0;
    int sc = v;
    #pragma unroll
    for (int off = 1; off < 64; off <<= 1) {
        int t = __shfl_up(sc, off);
        if (lane >= off) sc += t;
    }
    if (lane == 63) wsum[w] = sc;
    __syncthreads();
    if (tid == 0) {
        int s0 = wsum[0], s1 = wsum[1], s2 = wsum[2], s3 = wsum[3];
        wsum[0] = 0; wsum[1] = s0; wsum[2] = s0 + s1; wsum[3] = s0 + s1 + s2;
        bsum[blockIdx.x] = s0 + s1 + s2 + s3;
    }
    __syncthreads();
    if (i < N_NODES) rowptr[i] = sc - v + wsum[w];   // block-local exclusive

    // last block to arrive scans the 196 block sums in place
    __threadfence();                                 // publish bsum/rowptr
    if (tid == 0) amLast = (atomicAdd(done, 1) == SCAN_BLOCKS - 1);
    __syncthreads();
    if (!amLast) return;
    __threadfence();                                 // acquire others' bsum
    int v2 = (tid < SCAN_BLOCKS) ? bsum[tid] : 0;
    int sc2 = v2;
    #pragma unroll
    for (int off = 1; off < 64; off <<= 1) {
        int t = __shfl_up(sc2, off);
        if (lane >= off) sc2 += t;
    }
    __syncthreads();                                 // wsum reuse safe
    if (lane == 63) wsum[w] = sc2;
    __syncthreads();
    if (tid == 0) {
        int s0 = wsum[0], s1 = wsum[1], s2 = wsum[2];
        wsum[3] = s0 + s1 + s2; wsum[2] = s0 + s1; wsum[1] = s0; wsum[0] = 0;
    }
    __syncthreads();
    if (tid < SCAN_BLOCKS) bsum[tid] = sc2 - v2 + wsum[w];
}

// ---------------- K3: scatter (src, exp(score)) into CSR order -------------
// 8 edges/thread, no atomics (rank precomputed). ~24 independent random
// loads + 8 random 8B stores in flight per thread.
__global__ __launch_bounds__(256) void k_scatter(
        const int* __restrict__ src, const int* __restrict__ dst,
        const int* __restrict__ erank,
        const float* __restrict__ ssrc, const float* __restrict__ sdst,
        const int* __restrict__ rowptr, const int* __restrict__ bsum,
        uint2* __restrict__ sev) {
    int e0 = (blockIdx.x * 256 + threadIdx.x) * 8;
    if (e0 >= E_EDGES) return;                // 800000 % 8 == 0
    int sv[8], dv[8], rk[8];
    *(int4*)&sv[0] = *(const int4*)&src[e0];
    *(int4*)&sv[4] = *(const int4*)&src[e0 + 4];
    *(int4*)&dv[0] = *(const int4*)&dst[e0];
    *(int4*)&dv[4] = *(const int4*)&dst[e0 + 4];
    *(int4*)&rk[0] = *(const int4*)&erank[e0];
    *(int4*)&rk[4] = *(const int4*)&erank[e0 + 4];
    float ssv[8], sdv[8];
    int rp[8], bs[8];
    #pragma unroll
    for (int q = 0; q < 8; ++q) {
        ssv[q] = ssrc[sv[q]];
        sdv[q] = sdst[dv[q]];
        rp[q]  = rowptr[dv[q]];
        bs[q]  = bsum[dv[q] >> 8];
    }
    #pragma unroll
    for (int q = 0; q < 8; ++q) {
        float sc = ssv[q] + sdv[q];
        sc = sc >= 0.f ? sc : 0.2f * sc;      // LeakyReLU(0.2)
        sev[rp[q] + bs[q] + rk[q]] =
            make_uint2((unsigned int)sv[q], __float_as_uint(__expf(sc)));
    }
}

// ---------------- K4: dim-sliced gather (4 slices x 32 dims) ---------------
// bid = nb*8 + x; slice = x>>1 (XCD pair via blockIdx%8 round-robin), node
// group = nb*2+(x&1). Wave = 1 node; lane = el*32+sl: el = edge parity
// (2 edges/iter), sl = dim within slice. Each edge fetches EXACTLY ONE 64B
// line from this XCD's L2-resident 3.2MB hb slice. Partial sums (32 dims,
// unnormalized) -> part[n][slice*32..]; slice 0 also writes den[n].
__global__ __launch_bounds__(256) void k_gslice(
        const int* __restrict__ rowptr, const int* __restrict__ bsum,
        const uint2* __restrict__ sev, const unsigned short* __restrict__ hb,
        float* __restrict__ part, float* __restrict__ den) {
    const int bid   = blockIdx.x;
    const int xb    = bid & 7;
    const int slice = xb >> 1;                 // 0..3
    const int grp   = (bid >> 3) * 2 + (xb & 1);   // 0..12499
    const int n     = __builtin_amdgcn_readfirstlane(grp * 4 + (threadIdx.x >> 6));
    const int lane  = threadIdx.x & 63;
    const int el    = lane >> 5, sl = lane & 31;
    int beg = rowptr[n] + bsum[n >> 8];
    int end = (n == N_NODES - 1) ? E_EDGES : rowptr[n + 1] + bsum[(n + 1) >> 8];
    const unsigned short* hs = hb + slice * 32 + sl;   // per-lane column base

    float a = 0.f, dn = 0.f;
    int i = beg;
    for (; i + 7 < end; i += 8) {
        i32x16v s0 = sload16(sev + __builtin_amdgcn_readfirstlane(i));
        #pragma unroll
        for (int q = 0; q < 4; ++q) {         // 2 edges per iteration
            int srcA = s0[4 * q], srcB = s0[4 * q + 2];
            float exA = __uint_as_float(s0[4 * q + 1]);
            float exB = __uint_as_float(s0[4 * q + 3]);
            int srcq = el ? srcB : srcA;
            unsigned short u = hs[(size_t)srcq * 128];  // one 64B line / edge
            float ex = el ? exB : exA;
            a  += ex * b2f(u);
            dn += exA + exB;
        }
    }
    for (; i < end; ++i) {
        i32x2v p2 = sload2(sev + __builtin_amdgcn_readfirstlane(i));
        unsigned short u = hs[(size_t)p2[0] * 128];
        float ex = __uint_as_float(p2[1]);
        a  += (el ? 0.f : ex * b2f(u));
        dn += ex;
    }
    a += __shfl_xor(a, 32);                    // combine edge-parity halves
    if (lane < 32) part[(size_t)n * 128 + slice * 32 + sl] = a;
    if (slice == 0 && lane == 0) den[n] = dn;
}

// ---------------- K5: finalize — alpha-normalize + residual + LayerNorm ----
__global__ __launch_bounds__(256) void k_final(
        const float* __restrict__ part, const float* __restrict__ den,
        const float* __restrict__ xin,
        const float* __restrict__ scale, const float* __restrict__ bias,
        float* __restrict__ out) {
    int n    = blockIdx.x * 4 + (threadIdx.x >> 6);
    int lane = threadIdx.x & 63;
    float dn = den[n];
    float inv_d = 1.f / (dn > 0.f ? dn : 1.f);
    size_t base = (size_t)n * 128 + 2 * lane;
    float2 pv = *(const float2*)&part[base];
    float2 xv = *(const float2*)&xin[base];
    float r0 = pv.x * inv_d + xv.x;
    float r1 = pv.y * inv_d + xv.y;

    float sum = r0 + r1;
    #pragma unroll
    for (int off = 32; off >= 1; off >>= 1) sum += __shfl_xor(sum, off);
    float mu = sum * (1.f / 128.f);
    float d0 = r0 - mu, d1 = r1 - mu;
    float ss = d0 * d0 + d1 * d1;
    #pragma unroll
    for (int off = 32; off >= 1; off >>= 1) ss += __shfl_xor(ss, off);
    float inv = rsqrtf(ss * (1.f / 128.f) + LN_EPS);
    float o0 = d0 * inv * scale[2 * lane]     + bias[2 * lane];
    float o1 = d1 * inv * scale[2 * lane + 1] + bias[2 * lane + 1];
    *(float2*)&out[base] = make_float2(o0, o1);
}

extern "C" void kernel_launch(void* const* d_in, const int* in_sizes, int n_in,
                              void* d_out, int out_size, void* d_ws, size_t ws_size,
                              hipStream_t stream) {
    const float* x        = (const float*)d_in[0];
    const float* W_lin    = (const float*)d_in[1];
    const float* W_attn   = (const float*)d_in[2];
    const float* ln_scale = (const float*)d_in[3];
    const float* ln_bias  = (const float*)d_in[4];
    const int*   edge     = (const int*)d_in[5];
    const int*   e_src    = edge;
    const int*   e_dst    = edge + E_EDGES;
    float* out = (float*)d_out;

    char* ws = (char*)d_ws;
    unsigned short* hb  = (unsigned short*)(ws);            // 12,800,000 B
    unsigned short* Whp = (unsigned short*)(ws + 12800000); //     32,768 B
    unsigned short* Wlp = (unsigned short*)(ws + 12832768); //     32,768 B
    float* ssrc   = (float*)(ws + 12865536);      //    200,000 B
    float* sdst   = (float*)(ws + 13065536);      //    200,000 B
    int*   count  = (int*)  (ws + 13265536);      //    200,000 B (degrees)
    int*   rowptr = (int*)  (ws + 13465536);      //    200,016 B (padded)
    int*   bsum   = (int*)  (ws + 13665552);      //        800 B (padded)
    uint2* sev    = (uint2*)(ws + 13666352);      //  6,400,000 B
    int*   erank  = (int*)  (ws + 20066352);      //  3,200,000 B
    float* part   = (float*)(ws + 23266432);      // 25,600,000 B (sliced partials)
    float* den    = (float*)(ws + 48866432);      //    200,000 B
    int*   done   = (int*)  (ws + 49066432);      //          4 B (scan flag)

    k_prep     <<<SCAN_BLOCKS, 256, 0, stream>>>(W_lin, Whp, Wlp, count, done);
    k_gemm_hist<<<GEMM_BLOCKS + HIST4_BLOCKS, 256, 0, stream>>>(
                    x, Whp, W_attn, e_dst, count, erank, hb, ssrc, sdst);
    k_scan     <<<SCAN_BLOCKS, 256, 0, stream>>>(count, rowptr, bsum, done);
    k_scatter  <<<SCAT_BLOCKS, 256, 0, stream>>>(e_src, e_dst, erank, ssrc, sdst,
                                                 rowptr, bsum, sev);
    k_gslice   <<<GSLICE_BLOCKS, 256, 0, stream>>>(rowptr, bsum, sev, hb, part, den);
    k_final    <<<FINAL_BLOCKS, 256, 0, stream>>>(part, den, x,
                                                  ln_scale, ln_bias, out);
}

// Round 5
// 189.930 us; speedup vs baseline: 1.3613x; 1.3613x over previous
//
#include <hip/hip_runtime.h>

#define N_NODES 50000
#define E_EDGES 800000
#define D_DIM   128
#define LN_EPS  1e-5f
#define SCAN_BLOCKS 196   // ceil(50000/256)
#define GEMM_BLOCKS 391   // ceil(50000/128)
#define HIST4_BLOCKS 782  // ceil(800000/1024), 4 edges/thread
#define SCAT_BLOCKS 1563  // ceil(800000/512), 2 edges/thread
#define GATH_BLOCKS 12500 // 4 nodes/block, 1 wave/node

typedef __bf16 bf16x8 __attribute__((ext_vector_type(8)));
typedef unsigned short ushort8v __attribute__((ext_vector_type(8)));
typedef float f32x4 __attribute__((ext_vector_type(4)));
typedef int i32x2v __attribute__((ext_vector_type(2)));
typedef int i32x16v __attribute__((ext_vector_type(16)));

// fp32 -> bf16 (round to nearest even), stored as raw ushort
__device__ inline unsigned short f2b(float f) {
    unsigned int u = __float_as_uint(f);
    unsigned int r = u + 0x7FFFu + ((u >> 16) & 1u);
    return (unsigned short)(r >> 16);
}
__device__ inline float b2f(unsigned short h) {
    return __uint_as_float((unsigned int)h << 16);
}
__device__ inline float blo(unsigned int u) { return __uint_as_float(u << 16); }
__device__ inline float bhi(unsigned int u) { return __uint_as_float(u & 0xFFFF0000u); }

// SMEM loads of wave-uniform sev batches. Issue WITHOUT waitcnt so two
// x16 loads overlap; swait() = explicit lgkmcnt(0) + sched_barrier(0)
// (rule #18: consumers must not be hoisted past the wait).
__device__ inline i32x16v sload16_nw(const uint2* p) {
    i32x16v r;
    asm volatile("s_load_dwordx16 %0, %1, 0x0" : "=&s"(r) : "s"(p));
    return r;
}
__device__ inline void swait() {
    asm volatile("s_waitcnt lgkmcnt(0)");
    __builtin_amdgcn_sched_barrier(0);
}
__device__ inline i32x2v sload2(const uint2* p) {
    i32x2v r;
    asm volatile("s_load_dwordx2 %0, %1, 0x0\n\ts_waitcnt lgkmcnt(0)"
                 : "=&s"(r) : "s"(p));
    return r;
}

// ---------------- K_prep: zero count/done; pack W into bf16 hi/lo B-frags --
__global__ void k_prep(const float* __restrict__ W,
                       unsigned short* __restrict__ Whp,
                       unsigned short* __restrict__ Wlp,
                       int* __restrict__ count, int* __restrict__ done) {
    int i = blockIdx.x * 256 + threadIdx.x;
    if (i == 0) *done = 0;
    if (i < N_NODES) count[i] = 0;
    if (i < 16384) {
        int o = i >> 7, k = i & 127;
        float v = W[i];                       // W[o][k], coalesced
        unsigned short h = f2b(v);
        unsigned short l = f2b(v - b2f(h));
        int idx = (k >> 3) * 1024 + o * 8 + (k & 7);
        Whp[idx] = h;
        Wlp[idx] = l;
    }
}

// ---------------- K1: fused [MFMA gemm blocks] + [hist/rank blocks] --------
// GEMM: h = x @ W^T via mfma_f32_16x16x32_bf16, 3-term bf16 split.
// Epilogue transposes acc through LDS (W buffer is dead) so hb stores are
// 8x16B coalesced per thread. Hist: 4 edges/thread, rank saved to erank.
__global__ __launch_bounds__(256, 2) void k_gemm_hist(
        const float* __restrict__ xin, const unsigned short* __restrict__ Wpk,
        const float* __restrict__ Wa, const int* __restrict__ dst,
        int* __restrict__ count, int* __restrict__ erank,
        unsigned short* __restrict__ hb,
        float* __restrict__ ssrc, float* __restrict__ sdst) {
    __shared__ float4 wl4[4096];   // 64 KB: [0,2048) = W hi, [2048,4096) = W lo
    const int tid = threadIdx.x;

    if (blockIdx.x >= GEMM_BLOCKS) {
        int e0 = (blockIdx.x - GEMM_BLOCKS) * 1024 + tid * 4;
        if (e0 < E_EDGES) {                   // e0 % 4 == 0 -> full quad valid
            int4 dv = *(const int4*)&dst[e0];
            int r0 = atomicAdd(&count[dv.x], 1);
            int r1 = atomicAdd(&count[dv.y], 1);
            int r2 = atomicAdd(&count[dv.z], 1);
            int r3 = atomicAdd(&count[dv.w], 1);
            *(int4*)&erank[e0] = make_int4(r0, r1, r2, r3);
        }
        return;
    }

    // stage packed W (hi plane then lo plane, contiguous 64 KB)
    {
        const float4* wsrc = (const float4*)Wpk;
        #pragma unroll
        for (int i = 0; i < 16; ++i)
            wl4[i * 256 + tid] = wsrc[i * 256 + tid];
    }

    const int c = tid & 15;          // A row / B col / D col within tile
    const int g = (tid >> 4) & 3;    // k-group within wave
    const int w = tid >> 6;          // wave id: rows w*32 .. w*32+31
    const int n0 = blockIdx.x * 128;

    // A fragments: rows n0 + w*32 + t*16 + c, k = s*32 + g*8 + j (j=0..7)
    bf16x8 ah[2][4], al[2][4];
    #pragma unroll
    for (int t = 0; t < 2; ++t) {
        int n = n0 + w * 32 + t * 16 + c;
        if (n > N_NODES - 1) n = N_NODES - 1;          // clamp tail rows
        const float* xr = xin + (size_t)n * 128;
        #pragma unroll
        for (int s = 0; s < 4; ++s) {
            float4 f0 = *(const float4*)(xr + s * 32 + g * 8);
            float4 f1 = *(const float4*)(xr + s * 32 + g * 8 + 4);
            float fv[8] = {f0.x, f0.y, f0.z, f0.w, f1.x, f1.y, f1.z, f1.w};
            ushort8v uh, ul;
            #pragma unroll
            for (int j = 0; j < 8; ++j) {
                unsigned short hj = f2b(fv[j]);
                uh[j] = hj;
                ul[j] = f2b(fv[j] - b2f(hj));
            }
            ah[t][s] = __builtin_bit_cast(bf16x8, uh);
            al[t][s] = __builtin_bit_cast(bf16x8, ul);
        }
    }

    __syncthreads();                 // LDS W staging complete
    const bf16x8* wb = (const bf16x8*)wl4;

    f32x4 acc[2][8];
    #pragma unroll
    for (int t = 0; t < 2; ++t)
        #pragma unroll
        for (int cb = 0; cb < 8; ++cb)
            acc[t][cb] = (f32x4){0.f, 0.f, 0.f, 0.f};

    #pragma unroll
    for (int cb = 0; cb < 8; ++cb) {
        #pragma unroll
        for (int s = 0; s < 4; ++s) {
            int q = (s * 4 + g) * 128 + cb * 16 + c;
            bf16x8 bh = wb[q];           // one ds_read_b128 each
            bf16x8 bl = wb[2048 + q];
            acc[0][cb] = __builtin_amdgcn_mfma_f32_16x16x32_bf16(ah[0][s], bh, acc[0][cb], 0, 0, 0);
            acc[1][cb] = __builtin_amdgcn_mfma_f32_16x16x32_bf16(ah[1][s], bh, acc[1][cb], 0, 0, 0);
            acc[0][cb] = __builtin_amdgcn_mfma_f32_16x16x32_bf16(al[0][s], bh, acc[0][cb], 0, 0, 0);
            acc[1][cb] = __builtin_amdgcn_mfma_f32_16x16x32_bf16(al[1][s], bh, acc[1][cb], 0, 0, 0);
            acc[0][cb] = __builtin_amdgcn_mfma_f32_16x16x32_bf16(ah[0][s], bl, acc[0][cb], 0, 0, 0);
            acc[1][cb] = __builtin_amdgcn_mfma_f32_16x16x32_bf16(ah[1][s], bl, acc[1][cb], 0, 0, 0);
        }
    }

    // ssrc/sdst: reduce across the 16 c-lanes (register-only, before LDS reuse)
    float asv[8], adv[8];
    #pragma unroll
    for (int cb = 0; cb < 8; ++cb) {
        asv[cb] = Wa[cb * 16 + c];
        adv[cb] = Wa[128 + cb * 16 + c];
    }
    #pragma unroll
    for (int t = 0; t < 2; ++t) {
        #pragma unroll
        for (int i = 0; i < 4; ++i) {
            int n = n0 + w * 32 + t * 16 + g * 4 + i;
            float ps = 0.f, pd = 0.f;
            #pragma unroll
            for (int cb = 0; cb < 8; ++cb) {
                float v = acc[t][cb][i];
                ps += v * asv[cb];
                pd += v * adv[cb];
            }
            #pragma unroll
            for (int off = 1; off < 16; off <<= 1) {
                ps += __shfl_xor(ps, off);
                pd += __shfl_xor(pd, off);
            }
            if (c == 0 && n < N_NODES) { ssrc[n] = ps; sdst[n] = pd; }
        }
    }

    // hb epilogue: transpose through LDS (W buffer dead), coalesced stores
    __syncthreads();                 // all waves done reading W from wl4
    unsigned short* hlds = (unsigned short*)wl4;   // [128][128] ushort = 32 KB
    #pragma unroll
    for (int t = 0; t < 2; ++t)
        #pragma unroll
        for (int cb = 0; cb < 8; ++cb)
            #pragma unroll
            for (int i = 0; i < 4; ++i)
                hlds[(w * 32 + t * 16 + g * 4 + i) * 128 + cb * 16 + c] =
                    f2b(acc[t][cb][i]);
    __syncthreads();
    #pragma unroll
    for (int ii = 0; ii < 8; ++ii) {
        int cidx = ii * 256 + tid;    // 2048 chunks of 16 B
        int row = cidx >> 4, off = cidx & 15;
        int n = n0 + row;
        if (n < N_NODES) {
            ushort8v v = *(const ushort8v*)&hlds[row * 128 + off * 8];
            *(ushort8v*)&hb[(size_t)n * 128 + off * 8] = v;
        }
    }
}

// ---------------- K2: fused two-level exclusive scan (last-block finishes) -
__global__ __launch_bounds__(256) void k_scan(const int* __restrict__ count,
                                              int* __restrict__ rowptr,
                                              int* __restrict__ bsum,
                                              int* __restrict__ done) {
    __shared__ int wsum[4];
    __shared__ int amLast;
    const int tid  = threadIdx.x;
    const int lane = tid & 63, w = tid >> 6;
    int i = blockIdx.x * 256 + tid;
    int v = (i < N_NODES) ? count[i] : 0;
    int sc = v;
    #pragma unroll
    for (int off = 1; off < 64; off <<= 1) {
        int t = __shfl_up(sc, off);
        if (lane >= off) sc += t;
    }
    if (lane == 63) wsum[w] = sc;
    __syncthreads();
    if (tid == 0) {
        int s0 = wsum[0], s1 = wsum[1], s2 = wsum[2], s3 = wsum[3];
        wsum[0] = 0; wsum[1] = s0; wsum[2] = s0 + s1; wsum[3] = s0 + s1 + s2;
        bsum[blockIdx.x] = s0 + s1 + s2 + s3;
    }
    __syncthreads();
    if (i < N_NODES) rowptr[i] = sc - v + wsum[w];   // block-local exclusive

    // last block to arrive scans the 196 block sums in place
    __threadfence();                                 // publish bsum/rowptr
    if (tid == 0) amLast = (atomicAdd(done, 1) == SCAN_BLOCKS - 1);
    __syncthreads();
    if (!amLast) return;
    __threadfence();                                 // acquire others' bsum
    int v2 = (tid < SCAN_BLOCKS) ? bsum[tid] : 0;
    int sc2 = v2;
    #pragma unroll
    for (int off = 1; off < 64; off <<= 1) {
        int t = __shfl_up(sc2, off);
        if (lane >= off) sc2 += t;
    }
    __syncthreads();                                 // wsum reuse safe
    if (lane == 63) wsum[w] = sc2;
    __syncthreads();
    if (tid == 0) {
        int s0 = wsum[0], s1 = wsum[1], s2 = wsum[2];
        wsum[3] = s0 + s1 + s2; wsum[2] = s0 + s1; wsum[1] = s0; wsum[0] = 0;
    }
    __syncthreads();
    if (tid < SCAN_BLOCKS) bsum[tid] = sc2 - v2 + wsum[w];
}

// ---------------- K3: scatter (src, exp(score)) into CSR order -------------
// 2 edges/thread, no atomics (rank precomputed). 1563 blocks = ~76% wave
// occupancy (r2's 782-block version was grid-limited at 48%).
__global__ __launch_bounds__(256) void k_scatter(
        const int* __restrict__ src, const int* __restrict__ dst,
        const int* __restrict__ erank,
        const float* __restrict__ ssrc, const float* __restrict__ sdst,
        const int* __restrict__ rowptr, const int* __restrict__ bsum,
        uint2* __restrict__ sev) {
    int e0 = (blockIdx.x * 256 + threadIdx.x) * 2;
    if (e0 >= E_EDGES) return;                // 800000 % 2 == 0, pair valid
    int2 sv = *(const int2*)&src[e0];
    int2 dv = *(const int2*)&dst[e0];
    int2 rk = *(const int2*)&erank[e0];
    float ss0 = ssrc[sv.x], ss1 = ssrc[sv.y];
    float sd0 = sdst[dv.x], sd1 = sdst[dv.y];
    int rp0 = rowptr[dv.x], rp1 = rowptr[dv.y];
    int bs0 = bsum[dv.x >> 8], bs1 = bsum[dv.y >> 8];
    float c0 = ss0 + sd0, c1 = ss1 + sd1;
    c0 = c0 >= 0.f ? c0 : 0.2f * c0;          // LeakyReLU(0.2)
    c1 = c1 >= 0.f ? c1 : 0.2f * c1;
    sev[rp0 + bs0 + rk.x] = make_uint2((unsigned int)sv.x, __float_as_uint(__expf(c0)));
    sev[rp1 + bs1 + rk.y] = make_uint2((unsigned int)sv.y, __float_as_uint(__expf(c1)));
}

// ---------------- K4: per-node gather-aggregate + fused residual+LN --------
// One wave per node; lane l handles dims 2l, 2l+1. sev batches via the
// SCALAR pipe; both x16 s_loads issued before one wait (latency overlap).
// hb row addressing is SALU + saddr-form loads (voffset = 4*lane).
__global__ __launch_bounds__(256) void k_gather(
        const int* __restrict__ rowptr, const int* __restrict__ bsum,
        const uint2* __restrict__ sev,
        const unsigned short* __restrict__ hb, const float* __restrict__ x,
        const float* __restrict__ scale, const float* __restrict__ bias,
        float* __restrict__ out) {
    int n    = __builtin_amdgcn_readfirstlane(blockIdx.x * 4 + (threadIdx.x >> 6));
    int lane = threadIdx.x & 63;
    int beg = rowptr[n] + bsum[n >> 8];
    int end = (n == N_NODES - 1) ? E_EDGES : rowptr[n + 1] + bsum[(n + 1) >> 8];
    const unsigned int* hb32 = (const unsigned int*)hb;

    float a0 = 0.f, a1 = 0.f, b0 = 0.f, b1 = 0.f, den = 0.f, den2 = 0.f;

    int i = beg;
    for (; i + 15 < end; i += 16) {           // 16 random hb loads in flight
        int ib = __builtin_amdgcn_readfirstlane(i);
        i32x16v s0 = sload16_nw(sev + ib);
        i32x16v s1 = sload16_nw(sev + ib + 8);
        swait();
        unsigned int u[16];
        #pragma unroll
        for (int q = 0; q < 8; ++q)
            u[q] = hb32[(((unsigned)s0[2 * q]) << 6) + lane];
        #pragma unroll
        for (int q = 0; q < 8; ++q)
            u[8 + q] = hb32[(((unsigned)s1[2 * q]) << 6) + lane];
        #pragma unroll
        for (int q = 0; q < 8; q += 2) {
            float ex0 = __uint_as_float(s0[2 * q + 1]);
            float ex1 = __uint_as_float(s0[2 * q + 3]);
            den  += ex0; den2 += ex1;
            a0 += ex0 * blo(u[q]);     a1 += ex0 * bhi(u[q]);
            b0 += ex1 * blo(u[q + 1]); b1 += ex1 * bhi(u[q + 1]);
        }
        #pragma unroll
        for (int q = 0; q < 8; q += 2) {
            float ex0 = __uint_as_float(s1[2 * q + 1]);
            float ex1 = __uint_as_float(s1[2 * q + 3]);
            den  += ex0; den2 += ex1;
            a0 += ex0 * blo(u[8 + q]);     a1 += ex0 * bhi(u[8 + q]);
            b0 += ex1 * blo(u[8 + q + 1]); b1 += ex1 * bhi(u[8 + q + 1]);
        }
    }
    for (; i + 7 < end; i += 8) {
        int ib = __builtin_amdgcn_readfirstlane(i);
        i32x16v s0 = sload16_nw(sev + ib);
        swait();
        unsigned int u[8];
        #pragma unroll
        for (int q = 0; q < 8; ++q)
            u[q] = hb32[(((unsigned)s0[2 * q]) << 6) + lane];
        #pragma unroll
        for (int q = 0; q < 8; q += 2) {
            float ex0 = __uint_as_float(s0[2 * q + 1]);
            float ex1 = __uint_as_float(s0[2 * q + 3]);
            den  += ex0; den2 += ex1;
            a0 += ex0 * blo(u[q]);     a1 += ex0 * bhi(u[q]);
            b0 += ex1 * blo(u[q + 1]); b1 += ex1 * bhi(u[q + 1]);
        }
    }
    for (; i < end; ++i) {
        i32x2v p2 = sload2(sev + __builtin_amdgcn_readfirstlane(i));
        unsigned int u0 = hb32[(((unsigned)p2[0]) << 6) + lane];
        float ex0 = __uint_as_float(p2[1]);
        den += ex0;
        a0 += ex0 * blo(u0);
        a1 += ex0 * bhi(u0);
    }
    a0 += b0; a1 += b1; den += den2;

    float inv_d = 1.f / (den > 0.f ? den : 1.f);
    size_t base = (size_t)n * 128 + 2 * lane;
    float2 xv = *(const float2*)&x[base];
    float r0 = a0 * inv_d + xv.x;
    float r1 = a1 * inv_d + xv.y;

    float sum = r0 + r1;
    #pragma unroll
    for (int off = 32; off >= 1; off >>= 1) sum += __shfl_xor(sum, off);
    float mu = sum * (1.f / 128.f);
    float d0 = r0 - mu, d1 = r1 - mu;
    float ss = d0 * d0 + d1 * d1;
    #pragma unroll
    for (int off = 32; off >= 1; off >>= 1) ss += __shfl_xor(ss, off);
    float inv = rsqrtf(ss * (1.f / 128.f) + LN_EPS);
    float o0 = d0 * inv * scale[2 * lane]     + bias[2 * lane];
    float o1 = d1 * inv * scale[2 * lane + 1] + bias[2 * lane + 1];
    *(float2*)&out[base] = make_float2(o0, o1);
}

extern "C" void kernel_launch(void* const* d_in, const int* in_sizes, int n_in,
                              void* d_out, int out_size, void* d_ws, size_t ws_size,
                              hipStream_t stream) {
    const float* x        = (const float*)d_in[0];
    const float* W_lin    = (const float*)d_in[1];
    const float* W_attn   = (const float*)d_in[2];
    const float* ln_scale = (const float*)d_in[3];
    const float* ln_bias  = (const float*)d_in[4];
    const int*   edge     = (const int*)d_in[5];
    const int*   e_src    = edge;
    const int*   e_dst    = edge + E_EDGES;
    float* out = (float*)d_out;

    char* ws = (char*)d_ws;
    unsigned short* hb  = (unsigned short*)(ws);            // 12,800,000 B
    unsigned short* Whp = (unsigned short*)(ws + 12800000); //     32,768 B
    unsigned short* Wlp = (unsigned short*)(ws + 12832768); //     32,768 B
    float* ssrc   = (float*)(ws + 12865536);      //    200,000 B
    float* sdst   = (float*)(ws + 13065536);      //    200,000 B
    int*   count  = (int*)  (ws + 13265536);      //    200,000 B (degrees)
    int*   rowptr = (int*)  (ws + 13465536);      //    200,016 B (padded)
    int*   bsum   = (int*)  (ws + 13665552);      //        800 B (padded)
    uint2* sev    = (uint2*)(ws + 13666352);      //  6,400,000 B
    int*   erank  = (int*)  (ws + 20066352);      //  3,200,000 B
    int*   done   = (int*)  (ws + 23266352);      //          4 B (scan flag)

    k_prep     <<<SCAN_BLOCKS, 256, 0, stream>>>(W_lin, Whp, Wlp, count, done);
    k_gemm_hist<<<GEMM_BLOCKS + HIST4_BLOCKS, 256, 0, stream>>>(
                    x, Whp, W_attn, e_dst, count, erank, hb, ssrc, sdst);
    k_scan     <<<SCAN_BLOCKS, 256, 0, stream>>>(count, rowptr, bsum, done);
    k_scatter  <<<SCAT_BLOCKS, 256, 0, stream>>>(e_src, e_dst, erank, ssrc, sdst,
                                                 rowptr, bsum, sev);
    k_gather   <<<GATH_BLOCKS, 256, 0, stream>>>(rowptr, bsum, sev, hb, x,
                                                 ln_scale, ln_bias, out);
}